// Round 9
// baseline (277.031 us; speedup 1.0000x reference)
//
#include <hip/hip_runtime.h>

// Attention block: qkv proj -> RoPE -> causal GQA flash attention -> out proj.
// B=1, S=2048, H=2048, NH=32, KVH=8, D=64, G=4.
// R8:  gemm rework (8 waves, wave-pair split-K). flash ~49us.
// R15 (win, 49.5->45): <=4-tile chunks, 2304 blocks, bf16 partials.
// R16 (regressed 50): MFMA-ones lsum added a serial MFMA dep chain per tile;
//      VALU fell as predicted but latency rose. Reverted.
// R17: R15 softmax restored (independent VALU lsum + lbuf epilogue, exp2-fma
//      kept). KVBLK 64->32: LDS 16KB dbuf -> __launch_bounds__(256,6),
//      6 blocks/CU; tile latency halves, chunk key-span unchanged (<=8 tiles
//      of 32 keys = 256 keys) so pbuf/flash_reduce layout provably identical
//      (ceil(((q>>1)+1)/4) == ceil((q+1)/8) for all q). V-tile rows are 64B:
//      write-side pre-swizzled source chunk j^(d&3), read chunk quad^(c&3).

typedef __bf16 bf16_t;
typedef __attribute__((ext_vector_type(8))) __bf16 bf16x8;
typedef __attribute__((ext_vector_type(4))) __bf16 bf16x4;
typedef __attribute__((ext_vector_type(4))) float f32x4;
typedef __attribute__((ext_vector_type(2))) unsigned int u32x2;
typedef __attribute__((ext_vector_type(4))) unsigned int u32x4;

#define S_LEN 2048
#define H_DIM 2048
#define NHEAD 32
#define KVH 8
#define HD 64
#define QKV_N 3072  // (NH + 2*KVH) * D

// split-K chunking: qt 0..7 direct (T=qt+1 <= 8 tiles of 32 keys);
// qt 8..63 split into ceil((qt+1)/8) chunks. Per kh: 8 direct + 280 split.
#define NE_PER_KH 288
#define NSPLIT_PER_KH 280
// partial entry: 4h*32r*64d bf16 (16384B) + 4h*32r lsum f32 (512B)
#define ENT_BYTES 16896

// ---------------- fused cast fp32 -> bf16 (x, w_qkv, w_o) ----------------
__global__ void cast3_kernel(const float* __restrict__ x, const float* __restrict__ wq,
                             const float* __restrict__ wo, bf16_t* __restrict__ xb,
                             bf16_t* __restrict__ wqb, bf16_t* __restrict__ wob) {
  int i = blockIdx.x * blockDim.x + threadIdx.x;
  const int n1 = S_LEN * H_DIM / 4, n2 = QKV_N * H_DIM / 4, n3 = H_DIM * H_DIM / 4;
  const float* src; bf16_t* dst; int j;
  if (i < n1)           { src = x;  dst = xb;  j = i; }
  else if (i < n1 + n2) { src = wq; dst = wqb; j = i - n1; }
  else if (i < n1 + n2 + n3) { src = wo; dst = wob; j = i - n1 - n2; }
  else return;
  float4 v = ((const float4*)src)[j];
  bf16x4 o;
  o.x = (bf16_t)v.x; o.y = (bf16_t)v.y; o.z = (bf16_t)v.z; o.w = (bf16_t)v.w;
  ((bf16x4*)dst)[j] = o;
}

// ---------------- async 16B global -> LDS ----------------
__device__ __forceinline__ void async_copy16(bf16_t* lds_base, const bf16_t* g) {
  __builtin_amdgcn_global_load_lds(
      (const __attribute__((address_space(1))) unsigned int*)g,
      (__attribute__((address_space(3))) unsigned int*)lds_base, 16, 0, 0);
}

// ---------------- GEMM: C[M,N] = A[M,K] * B[N,K]^T (bf16 in) ----------------
#define GBM 128
#define GBN 128

template <int EPI>
__global__ __launch_bounds__(512, 4) void gemm_sk(const bf16_t* __restrict__ A,
                                                  const bf16_t* __restrict__ B,
                                                  float* __restrict__ C,
                                                  bf16_t* __restrict__ qb,
                                                  bf16_t* __restrict__ ktp,
                                                  bf16_t* __restrict__ vt2,
                                                  int M, int N, int K) {
  __shared__ __align__(16) bf16_t As[2][GBM * 64];
  __shared__ __align__(16) bf16_t Bs[2][GBM * 64];

  const int tid  = threadIdx.x;
  const int lane = tid & 63;
  const int w    = tid >> 6;          // 0..7
  const int wq   = w & 3;             // pair id / subtile
  const int gw   = w >> 2;            // K32 group
  const int wm   = (wq >> 1) * 64;
  const int wn   = (wq & 1) * 64;
  const int c    = lane & 15;
  const int quad = lane >> 4;
  const int m0   = blockIdx.y * GBM;
  const int n0   = blockIdx.x * GBN;

  f32x4 acc[4][4] = {};

  const bf16_t* Ab = A + (size_t)m0 * K;
  const bf16_t* Bb = B + (size_t)n0 * K;

  int srow[2], skc[2], sb[2];
#pragma unroll
  for (int i = 0; i < 2; ++i) {
    int p = i * 512 + tid;
    srow[i] = p >> 3;
    skc[i]  = (p & 7) ^ (srow[i] & 7);
    sb[i]   = (i * 512 + w * 64) * 8;   // wave-uniform element base
  }

  auto stage = [&](int buf, int k0) {
#pragma unroll
    for (int i = 0; i < 2; ++i) {
      async_copy16(&As[buf][sb[i]], Ab + (size_t)srow[i] * K + k0 + skc[i] * 8);
      async_copy16(&Bs[buf][sb[i]], Bb + (size_t)srow[i] * K + k0 + skc[i] * 8);
    }
  };

  auto compute = [&](int buf) {
    bf16x8 af[4], bfr[4];
#pragma unroll
    for (int mt = 0; mt < 4; ++mt) {
      int row = wm + mt * 16 + c;
      af[mt] = *(const bf16x8*)&As[buf][(row * 8 + ((gw * 4 + quad) ^ (row & 7))) * 8];
    }
#pragma unroll
    for (int nt = 0; nt < 4; ++nt) {
      int rowb = wn + nt * 16 + c;
      bfr[nt] = *(const bf16x8*)&Bs[buf][(rowb * 8 + ((gw * 4 + quad) ^ (rowb & 7))) * 8];
    }
#pragma unroll
    for (int mt = 0; mt < 4; ++mt)
#pragma unroll
      for (int nt = 0; nt < 4; ++nt)
        acc[mt][nt] = __builtin_amdgcn_mfma_f32_16x16x32_bf16(af[mt], bfr[nt], acc[mt][nt], 0, 0, 0);
  };

  const int NI = K >> 6;   // BK=64 iterations
  stage(0, 0);
  int buf = 0;
  for (int it = 0; it < NI; ++it) {
    asm volatile("s_waitcnt vmcnt(0)" ::: "memory");
    __builtin_amdgcn_s_barrier();
    if (it + 1 < NI) stage(buf ^ 1, (it + 1) << 6);
    compute(buf);
    buf ^= 1;
  }

  __syncthreads();
  float* xch = (float*)&As[0][0];
  if (gw == 1) {
#pragma unroll
    for (int t16 = 0; t16 < 16; ++t16)
      *(f32x4*)&xch[wq * 4096 + (t16 * 64 + lane) * 4] = acc[t16 >> 2][t16 & 3];
  }
  __syncthreads();
  if (gw == 0) {
#pragma unroll
    for (int t16 = 0; t16 < 16; ++t16) {
      f32x4 o = *(const f32x4*)&xch[wq * 4096 + (t16 * 64 + lane) * 4];
      acc[t16 >> 2][t16 & 3] += o;
    }

    if (EPI == 0) {
#pragma unroll
      for (int mt = 0; mt < 4; ++mt)
#pragma unroll
        for (int nt = 0; nt < 4; ++nt)
#pragma unroll
          for (int reg = 0; reg < 4; ++reg) {
            int row = m0 + wm + mt * 16 + quad * 4 + reg;
            int col = n0 + wn + nt * 16 + c;
            C[(size_t)row * N + col] = acc[mt][nt][reg];
          }
    } else {
      const int colb = n0 + wn;
      if (colb < NHEAD * HD) {
        const int h = colb >> 6;
#pragma unroll
        for (int nt = 0; nt < 2; ++nt) {
          const int i = nt * 16 + c;
          const float invf = __expf(-(float)i * (9.210340371976184f / 32.0f));
#pragma unroll
          for (int mt = 0; mt < 4; ++mt)
#pragma unroll
            for (int reg = 0; reg < 4; ++reg) {
              const int s = m0 + wm + mt * 16 + quad * 4 + reg;
              float sn, cs;
              __sincosf((float)s * invf, &sn, &cs);
              const float x1 = acc[mt][nt][reg], x2 = acc[mt][nt + 2][reg];
              bf16_t* q = qb + (size_t)s * H_DIM + h * HD;
              q[i]      = (bf16_t)((x1 * cs - x2 * sn) * 0.125f);
              q[i + 32] = (bf16_t)((x2 * cs + x1 * sn) * 0.125f);
            }
        }
      } else if (colb < NHEAD * HD + KVH * HD) {
        const int kh = (colb - NHEAD * HD) >> 6;
#pragma unroll
        for (int nt = 0; nt < 2; ++nt) {
          const int i = nt * 16 + c;
          const float invf = __expf(-(float)i * (9.210340371976184f / 32.0f));
#pragma unroll
          for (int mt = 0; mt < 4; ++mt)
#pragma unroll
            for (int reg = 0; reg < 4; ++reg) {
              const int s = m0 + wm + mt * 16 + quad * 4 + reg;
              float sn, cs;
              __sincosf((float)s * invf, &sn, &cs);
              const float x1 = acc[mt][nt][reg], x2 = acc[mt][nt + 2][reg];
              bf16_t* kd = ktp + ((size_t)kh * S_LEN + s) * HD;
              kd[i]      = (bf16_t)(x1 * cs - x2 * sn);
              kd[i + 32] = (bf16_t)(x2 * cs + x1 * sn);
            }
        }
      } else {
        const int kh = (colb - NHEAD * HD - KVH * HD) >> 6;
#pragma unroll
        for (int nt = 0; nt < 4; ++nt) {
          const int d = nt * 16 + c;
#pragma unroll
          for (int mt = 0; mt < 4; ++mt) {
            const int sr = m0 + wm + mt * 16 + quad * 4;
            bf16x4 pv;
#pragma unroll
            for (int reg = 0; reg < 4; ++reg) pv[reg] = (bf16_t)acc[mt][nt][reg];
            *(bf16x4*)&vt2[((size_t)kh * HD + d) * S_LEN + sr] = pv;
          }
        }
      }
    }
  }
}

// ---------------- split-K MFMA flash (KVBLK=32) ----------------
// bpermute P redistribution (R14), chunked decomposition (R15), 32-key tiles
// double-buffered in 16KB LDS (R17): Ks[2][32x64] 128B rows (XOR c&7 chunks),
// Vs[2][64x32] 64B rows (XOR c&3 chunks), 6 blocks/CU.
__global__ __launch_bounds__(256, 6) void flash_split(const bf16_t* __restrict__ qb,
                                                      const bf16_t* __restrict__ kt,
                                                      const bf16_t* __restrict__ vt2,
                                                      float* __restrict__ pbuf,
                                                      bf16_t* __restrict__ attn) {
  __shared__ __align__(16) bf16_t Ks[2][32 * 64];
  __shared__ __align__(16) bf16_t Vs[2][64 * 32];

  const int tid  = threadIdx.x;
  const int lane = tid & 63;
  const int w    = tid >> 6;
  const int e    = (int)gridDim.x - 1 - (int)blockIdx.x;   // long chunks first
  const int kh   = e / NE_PER_KH;
  const int j    = e - kh * NE_PER_KH;

  int qt, chunk, nch;
  if (j < 8) {
    qt = j; chunk = 0; nch = 1;
  } else {
    int j2 = j - 8;
    qt = 8;
    for (;;) {
      nch = (qt + 8) >> 3;          // ceil((qt+1)/8)
      if (j2 < nch) { chunk = j2; break; }
      j2 -= nch; ++qt;
    }
  }
  const int T       = qt + 1;       // 32-key tiles
  const int t_begin = (chunk * T) / nch;
  const int t_end   = ((chunk + 1) * T) / nch;

  const int s0    = qt * 32;
  const int h     = kh * 4 + w;
  const int c     = lane & 15;
  const int quad  = lane >> 4;

  // loop-invariant bpermute source-lane indices (bytes)
  const int idx0 = (c + (quad & 1) * 32) * 4;
  const int idx1 = idx0 + 64;
  const bool hiY = quad >= 2;

  bf16x8 qf[2][2];
#pragma unroll
  for (int rf = 0; rf < 2; ++rf)
#pragma unroll
    for (int ks = 0; ks < 2; ++ks)
      qf[rf][ks] = *(const bf16x8*)(qb + (size_t)(s0 + rf * 16 + c) * H_DIM + h * HD + ks * 32 + quad * 8);

  f32x4 acc[2][4] = {};
  float lsum[2] = {0.f, 0.f};

  const bf16_t* kbase = kt + (size_t)kh * S_LEN * HD;
  const bf16_t* vbase = vt2 + (size_t)kh * HD * S_LEN;

  // staging: 256 16B chunks each for K and V per tile; thread tid owns chunk tid.
  // K: row = tid>>3 (32 rows x 128B), src chunk = (tid&7)^(row&7).
  // V: row d = tid>>2 (64 rows x 64B),  src chunk = (tid&3)^(d&3).
  const int krow = tid >> 3;
  const int kkc  = (tid & 7) ^ (krow & 7);
  const int vrow = tid >> 2;
  const int vkc  = (tid & 3) ^ (vrow & 3);
  const int sbase = w * 64 * 8;   // wave-uniform element base (lane*16B auto)

  auto stage = [&](int buf, int tile) {
    const int t0 = tile * 32;
    async_copy16(&Ks[buf][sbase], kbase + (size_t)(t0 + krow) * HD + kkc * 8);
    async_copy16(&Vs[buf][sbase], vbase + (size_t)vrow * S_LEN + t0 + vkc * 8);
  };

  stage(0, t_begin);
  int buf = 0;
  for (int tile = t_begin; tile < t_end; ++tile) {
    const int t0 = tile * 32;
    asm volatile("s_waitcnt vmcnt(0)" ::: "memory");
    __builtin_amdgcn_s_barrier();
    if (tile + 1 < t_end) stage(buf ^ 1, tile + 1);

    const bool masked = (tile == T - 1);

    unsigned pw[2][2][2];   // [rf][kt2][word]
#pragma unroll
    for (int kt2 = 0; kt2 < 2; ++kt2) {
      bf16x8 kf0 = *(const bf16x8*)&Ks[buf][((kt2 * 16 + c) * 8 + ((quad) ^ (c & 7))) * 8];
      bf16x8 kf1 = *(const bf16x8*)&Ks[buf][((kt2 * 16 + c) * 8 + ((4 + quad) ^ (c & 7))) * 8];
#pragma unroll
      for (int rf = 0; rf < 2; ++rf) {
        f32x4 st = {};
        __builtin_amdgcn_s_setprio(1);
        st = __builtin_amdgcn_mfma_f32_16x16x32_bf16(kf0, qf[rf][0], st, 0, 0, 0);
        st = __builtin_amdgcn_mfma_f32_16x16x32_bf16(kf1, qf[rf][1], st, 0, 0, 0);
        __builtin_amdgcn_s_setprio(0);
        const int row = s0 + rf * 16 + c;
        bf16x4 pk;
#pragma unroll
        for (int reg = 0; reg < 4; ++reg) {
          const int key = t0 + kt2 * 16 + quad * 4 + reg;
          float p = __builtin_amdgcn_exp2f(fmaf(st[reg], 1.44269504f, -11.54156036f));
          if (masked && key > row) p = 0.f;
          pk[reg] = (bf16_t)p;
          lsum[rf] += p;
        }
        u32x2 pv2 = __builtin_bit_cast(u32x2, pk);
        pw[rf][kt2][0] = pv2.x;
        pw[rf][kt2][1] = pv2.y;
      }
    }

    bf16x8 vf[4];
#pragma unroll
    for (int dt = 0; dt < 4; ++dt)
      vf[dt] = *(const bf16x8*)&Vs[buf][((dt * 16 + c) * 4 + (quad ^ (c & 3))) * 8];

#pragma unroll
    for (int rf = 0; rf < 2; ++rf) {
      int lo, hi;
      u32x4 fwv;
      lo = __builtin_amdgcn_ds_bpermute(idx0, (int)pw[rf][0][0]);
      hi = __builtin_amdgcn_ds_bpermute(idx0, (int)pw[rf][1][0]);
      fwv.x = hiY ? (unsigned)hi : (unsigned)lo;
      lo = __builtin_amdgcn_ds_bpermute(idx0, (int)pw[rf][0][1]);
      hi = __builtin_amdgcn_ds_bpermute(idx0, (int)pw[rf][1][1]);
      fwv.y = hiY ? (unsigned)hi : (unsigned)lo;
      lo = __builtin_amdgcn_ds_bpermute(idx1, (int)pw[rf][0][0]);
      hi = __builtin_amdgcn_ds_bpermute(idx1, (int)pw[rf][1][0]);
      fwv.z = hiY ? (unsigned)hi : (unsigned)lo;
      lo = __builtin_amdgcn_ds_bpermute(idx1, (int)pw[rf][0][1]);
      hi = __builtin_amdgcn_ds_bpermute(idx1, (int)pw[rf][1][1]);
      fwv.w = hiY ? (unsigned)hi : (unsigned)lo;
      bf16x8 pa = __builtin_bit_cast(bf16x8, fwv);
      __builtin_amdgcn_s_setprio(1);
#pragma unroll
      for (int dt = 0; dt < 4; ++dt)
        acc[rf][dt] = __builtin_amdgcn_mfma_f32_16x16x32_bf16(pa, vf[dt], acc[rf][dt], 0, 0, 0);
      __builtin_amdgcn_s_setprio(0);
    }
    buf ^= 1;
  }

#pragma unroll
  for (int rf = 0; rf < 2; ++rf) {
    lsum[rf] += __shfl_xor(lsum[rf], 16);
    lsum[rf] += __shfl_xor(lsum[rf], 32);
  }

  __syncthreads();   // all Ks readers done before reusing Ks as lbuf
  if (j < 8) {
    float* lbuf = (float*)&Ks[0][0] + w * 32;
#pragma unroll
    for (int rf = 0; rf < 2; ++rf) lbuf[rf * 16 + c] = lsum[rf];
    asm volatile("s_waitcnt lgkmcnt(0)" ::: "memory");
#pragma unroll
    for (int rf = 0; rf < 2; ++rf)
#pragma unroll
      for (int reg = 0; reg < 4; ++reg) {
        const float inv = 1.0f / lbuf[rf * 16 + quad * 4 + reg];
        const int row = s0 + rf * 16 + quad * 4 + reg;
#pragma unroll
        for (int dt = 0; dt < 4; ++dt)
          attn[(size_t)row * H_DIM + h * HD + dt * 16 + c] = (bf16_t)(acc[rf][dt][reg] * inv);
      }
  } else {
    const int slot = kh * NSPLIT_PER_KH + (j - 8);
    char* ent = (char*)pbuf + (size_t)slot * ENT_BYTES;
    bf16_t* eo = (bf16_t*)ent;
    float*  el = (float*)(ent + 16384);
#pragma unroll
    for (int rf = 0; rf < 2; ++rf) {
#pragma unroll
      for (int dt = 0; dt < 4; ++dt)
#pragma unroll
        for (int reg = 0; reg < 4; ++reg)
          eo[w * 2048 + (rf * 16 + quad * 4 + reg) * 64 + dt * 16 + c] = (bf16_t)acc[rf][dt][reg];
      el[w * 32 + rf * 16 + c] = lsum[rf];
    }
  }
}

// ---------------- reduce: sum bf16 partial chunks, normalize, write attn ----
// one block per (kh, qt>=8): 8*56 = 448 blocks. nch = ceil((qt+1)/8) —
// identical values to the R15 layout.
__global__ __launch_bounds__(256) void flash_reduce(const float* __restrict__ pbuf,
                                                    bf16_t* __restrict__ attn) {
  const int kh = blockIdx.x / 56;
  const int qt = 8 + (blockIdx.x % 56);

  int base = 0;
  for (int q = 8; q < qt; ++q) base += (q + 8) >> 3;
  const int nch = (qt + 8) >> 3;
  base += kh * NSPLIT_PER_KH;

  const int t   = threadIdx.x;
  const int h2  = t >> 6;
  const int row = (t >> 1) & 31;
  const int dh  = t & 1;

  f32x4 o[8] = {};
  float l = 0.f;
  for (int ci = 0; ci < nch; ++ci) {
    const char* ent = (const char*)pbuf + (size_t)(base + ci) * ENT_BYTES;
    const bf16_t* p = (const bf16_t*)ent + h2 * 2048 + row * 64 + dh * 32;
#pragma unroll
    for (int jj = 0; jj < 8; ++jj) {
      bf16x4 v = ((const bf16x4*)p)[jj];
      o[jj][0] += (float)v[0]; o[jj][1] += (float)v[1];
      o[jj][2] += (float)v[2]; o[jj][3] += (float)v[3];
    }
    l += ((const float*)(ent + 16384))[h2 * 32 + row];
  }
  const float inv = 1.0f / l;
  bf16_t* dst = attn + (size_t)(qt * 32 + row) * H_DIM + (kh * 4 + h2) * 64 + dh * 32;
#pragma unroll
  for (int jj = 0; jj < 8; ++jj) {
    bf16x4 ov;
    ov[0] = (bf16_t)(o[jj][0] * inv); ov[1] = (bf16_t)(o[jj][1] * inv);
    ov[2] = (bf16_t)(o[jj][2] * inv); ov[3] = (bf16_t)(o[jj][3] * inv);
    *(bf16x4*)(dst + jj * 4) = ov;
  }
}

// ---------------- launch ----------------
extern "C" void kernel_launch(void* const* d_in, const int* in_sizes, int n_in,
                              void* d_out, int out_size, void* d_ws, size_t ws_size,
                              hipStream_t stream) {
  const float* x     = (const float*)d_in[0];
  const float* w_qkv = (const float*)d_in[1];
  const float* w_o   = (const float*)d_in[2];
  float* out = (float*)d_out;

  char* ws = (char*)d_ws;
  const size_t OVERLAY = (size_t)1280 * 8320 * 4;  // 42.6 MB (pbuf needs 36.1MB)
  bf16_t* x_bf    = (bf16_t*)ws;
  bf16_t* wqkv_bf = (bf16_t*)(ws + (size_t)S_LEN * H_DIM * 2);
  float*  pbuf    = (float*)ws;
  size_t off = OVERLAY;
  bf16_t* wo_bf   = (bf16_t*)(ws + off); off += (size_t)H_DIM * H_DIM * 2;
  bf16_t* q_bf    = (bf16_t*)(ws + off); off += (size_t)S_LEN * H_DIM * 2;
  bf16_t* k_t     = (bf16_t*)(ws + off); off += (size_t)KVH * S_LEN * HD * 2;
  bf16_t* v_t2    = (bf16_t*)(ws + off); off += (size_t)KVH * S_LEN * HD * 2;
  bf16_t* attn    = (bf16_t*)(ws + off); off += (size_t)S_LEN * H_DIM * 2;

  const int ntot = (S_LEN * H_DIM + QKV_N * H_DIM + H_DIM * H_DIM) / 4;
  cast3_kernel<<<(ntot + 255) / 256, 256, 0, stream>>>(x, w_qkv, w_o, x_bf, wqkv_bf, wo_bf);

  gemm_sk<1><<<dim3(QKV_N / GBN, S_LEN / GBM), 512, 0, stream>>>(
      x_bf, wqkv_bf, nullptr, q_bf, k_t, v_t2, S_LEN, QKV_N, H_DIM);

  flash_split<<<8 * NE_PER_KH, 256, 0, stream>>>(q_bf, k_t, v_t2, pbuf, attn);
  flash_reduce<<<8 * 56, 256, 0, stream>>>(pbuf, attn);

  gemm_sk<0><<<dim3(H_DIM / GBN, S_LEN / GBM), 512, 0, stream>>>(
      attn, wo_bf, out, nullptr, nullptr, nullptr, S_LEN, H_DIM, H_DIM);
}

// Round 10
// 217.553 us; speedup vs baseline: 1.2734x; 1.2734x over previous
//
#include <hip/hip_runtime.h>

// Attention block: qkv proj -> RoPE -> causal GQA flash attention -> out proj.
// B=1, S=2048, H=2048, NH=32, KVH=8, D=64, G=4.
// R8:  gemm rework (8 waves, wave-pair split-K). flash ~49us.
// R15 (win, 49.5->45): <=4-tile chunks, 2304 blocks, bf16 partials.
// R16 (regressed): MFMA-ones lsum serial dep chain. Reverted.
// R17 (regressed 106us): KVBLK=32 idea was right (occ 47%, passed) but
//      __launch_bounds__(256,6) capped VGPR ~85 < live ~95 -> spill
//      (VGPR_Count 40, FETCH 147MB, WRITE 167MB). Same failure mode as R12.
// R18: R17 with __launch_bounds__(256,4) (128-VGPR cap, no spill). 16KB LDS
//      -> residency capped by wave slots (8 blocks/CU), not LDS. RULE: never
//      set min-waves bound that caps VGPR below the ~95-reg live set.

typedef __bf16 bf16_t;
typedef __attribute__((ext_vector_type(8))) __bf16 bf16x8;
typedef __attribute__((ext_vector_type(4))) __bf16 bf16x4;
typedef __attribute__((ext_vector_type(4))) float f32x4;
typedef __attribute__((ext_vector_type(2))) unsigned int u32x2;
typedef __attribute__((ext_vector_type(4))) unsigned int u32x4;

#define S_LEN 2048
#define H_DIM 2048
#define NHEAD 32
#define KVH 8
#define HD 64
#define QKV_N 3072  // (NH + 2*KVH) * D

// split-K chunking: qt 0..7 direct (T=qt+1 <= 8 tiles of 32 keys);
// qt 8..63 split into ceil((qt+1)/8) chunks. Per kh: 8 direct + 280 split.
#define NE_PER_KH 288
#define NSPLIT_PER_KH 280
// partial entry: 4h*32r*64d bf16 (16384B) + 4h*32r lsum f32 (512B)
#define ENT_BYTES 16896

// ---------------- fused cast fp32 -> bf16 (x, w_qkv, w_o) ----------------
__global__ void cast3_kernel(const float* __restrict__ x, const float* __restrict__ wq,
                             const float* __restrict__ wo, bf16_t* __restrict__ xb,
                             bf16_t* __restrict__ wqb, bf16_t* __restrict__ wob) {
  int i = blockIdx.x * blockDim.x + threadIdx.x;
  const int n1 = S_LEN * H_DIM / 4, n2 = QKV_N * H_DIM / 4, n3 = H_DIM * H_DIM / 4;
  const float* src; bf16_t* dst; int j;
  if (i < n1)           { src = x;  dst = xb;  j = i; }
  else if (i < n1 + n2) { src = wq; dst = wqb; j = i - n1; }
  else if (i < n1 + n2 + n3) { src = wo; dst = wob; j = i - n1 - n2; }
  else return;
  float4 v = ((const float4*)src)[j];
  bf16x4 o;
  o.x = (bf16_t)v.x; o.y = (bf16_t)v.y; o.z = (bf16_t)v.z; o.w = (bf16_t)v.w;
  ((bf16x4*)dst)[j] = o;
}

// ---------------- async 16B global -> LDS ----------------
__device__ __forceinline__ void async_copy16(bf16_t* lds_base, const bf16_t* g) {
  __builtin_amdgcn_global_load_lds(
      (const __attribute__((address_space(1))) unsigned int*)g,
      (__attribute__((address_space(3))) unsigned int*)lds_base, 16, 0, 0);
}

// ---------------- GEMM: C[M,N] = A[M,K] * B[N,K]^T (bf16 in) ----------------
#define GBM 128
#define GBN 128

template <int EPI>
__global__ __launch_bounds__(512, 4) void gemm_sk(const bf16_t* __restrict__ A,
                                                  const bf16_t* __restrict__ B,
                                                  float* __restrict__ C,
                                                  bf16_t* __restrict__ qb,
                                                  bf16_t* __restrict__ ktp,
                                                  bf16_t* __restrict__ vt2,
                                                  int M, int N, int K) {
  __shared__ __align__(16) bf16_t As[2][GBM * 64];
  __shared__ __align__(16) bf16_t Bs[2][GBM * 64];

  const int tid  = threadIdx.x;
  const int lane = tid & 63;
  const int w    = tid >> 6;          // 0..7
  const int wq   = w & 3;             // pair id / subtile
  const int gw   = w >> 2;            // K32 group
  const int wm   = (wq >> 1) * 64;
  const int wn   = (wq & 1) * 64;
  const int c    = lane & 15;
  const int quad = lane >> 4;
  const int m0   = blockIdx.y * GBM;
  const int n0   = blockIdx.x * GBN;

  f32x4 acc[4][4] = {};

  const bf16_t* Ab = A + (size_t)m0 * K;
  const bf16_t* Bb = B + (size_t)n0 * K;

  int srow[2], skc[2], sb[2];
#pragma unroll
  for (int i = 0; i < 2; ++i) {
    int p = i * 512 + tid;
    srow[i] = p >> 3;
    skc[i]  = (p & 7) ^ (srow[i] & 7);
    sb[i]   = (i * 512 + w * 64) * 8;   // wave-uniform element base
  }

  auto stage = [&](int buf, int k0) {
#pragma unroll
    for (int i = 0; i < 2; ++i) {
      async_copy16(&As[buf][sb[i]], Ab + (size_t)srow[i] * K + k0 + skc[i] * 8);
      async_copy16(&Bs[buf][sb[i]], Bb + (size_t)srow[i] * K + k0 + skc[i] * 8);
    }
  };

  auto compute = [&](int buf) {
    bf16x8 af[4], bfr[4];
#pragma unroll
    for (int mt = 0; mt < 4; ++mt) {
      int row = wm + mt * 16 + c;
      af[mt] = *(const bf16x8*)&As[buf][(row * 8 + ((gw * 4 + quad) ^ (row & 7))) * 8];
    }
#pragma unroll
    for (int nt = 0; nt < 4; ++nt) {
      int rowb = wn + nt * 16 + c;
      bfr[nt] = *(const bf16x8*)&Bs[buf][(rowb * 8 + ((gw * 4 + quad) ^ (rowb & 7))) * 8];
    }
#pragma unroll
    for (int mt = 0; mt < 4; ++mt)
#pragma unroll
      for (int nt = 0; nt < 4; ++nt)
        acc[mt][nt] = __builtin_amdgcn_mfma_f32_16x16x32_bf16(af[mt], bfr[nt], acc[mt][nt], 0, 0, 0);
  };

  const int NI = K >> 6;   // BK=64 iterations
  stage(0, 0);
  int buf = 0;
  for (int it = 0; it < NI; ++it) {
    asm volatile("s_waitcnt vmcnt(0)" ::: "memory");
    __builtin_amdgcn_s_barrier();
    if (it + 1 < NI) stage(buf ^ 1, (it + 1) << 6);
    compute(buf);
    buf ^= 1;
  }

  __syncthreads();
  float* xch = (float*)&As[0][0];
  if (gw == 1) {
#pragma unroll
    for (int t16 = 0; t16 < 16; ++t16)
      *(f32x4*)&xch[wq * 4096 + (t16 * 64 + lane) * 4] = acc[t16 >> 2][t16 & 3];
  }
  __syncthreads();
  if (gw == 0) {
#pragma unroll
    for (int t16 = 0; t16 < 16; ++t16) {
      f32x4 o = *(const f32x4*)&xch[wq * 4096 + (t16 * 64 + lane) * 4];
      acc[t16 >> 2][t16 & 3] += o;
    }

    if (EPI == 0) {
#pragma unroll
      for (int mt = 0; mt < 4; ++mt)
#pragma unroll
        for (int nt = 0; nt < 4; ++nt)
#pragma unroll
          for (int reg = 0; reg < 4; ++reg) {
            int row = m0 + wm + mt * 16 + quad * 4 + reg;
            int col = n0 + wn + nt * 16 + c;
            C[(size_t)row * N + col] = acc[mt][nt][reg];
          }
    } else {
      const int colb = n0 + wn;
      if (colb < NHEAD * HD) {
        const int h = colb >> 6;
#pragma unroll
        for (int nt = 0; nt < 2; ++nt) {
          const int i = nt * 16 + c;
          const float invf = __expf(-(float)i * (9.210340371976184f / 32.0f));
#pragma unroll
          for (int mt = 0; mt < 4; ++mt)
#pragma unroll
            for (int reg = 0; reg < 4; ++reg) {
              const int s = m0 + wm + mt * 16 + quad * 4 + reg;
              float sn, cs;
              __sincosf((float)s * invf, &sn, &cs);
              const float x1 = acc[mt][nt][reg], x2 = acc[mt][nt + 2][reg];
              bf16_t* q = qb + (size_t)s * H_DIM + h * HD;
              q[i]      = (bf16_t)((x1 * cs - x2 * sn) * 0.125f);
              q[i + 32] = (bf16_t)((x2 * cs + x1 * sn) * 0.125f);
            }
        }
      } else if (colb < NHEAD * HD + KVH * HD) {
        const int kh = (colb - NHEAD * HD) >> 6;
#pragma unroll
        for (int nt = 0; nt < 2; ++nt) {
          const int i = nt * 16 + c;
          const float invf = __expf(-(float)i * (9.210340371976184f / 32.0f));
#pragma unroll
          for (int mt = 0; mt < 4; ++mt)
#pragma unroll
            for (int reg = 0; reg < 4; ++reg) {
              const int s = m0 + wm + mt * 16 + quad * 4 + reg;
              float sn, cs;
              __sincosf((float)s * invf, &sn, &cs);
              const float x1 = acc[mt][nt][reg], x2 = acc[mt][nt + 2][reg];
              bf16_t* kd = ktp + ((size_t)kh * S_LEN + s) * HD;
              kd[i]      = (bf16_t)(x1 * cs - x2 * sn);
              kd[i + 32] = (bf16_t)(x2 * cs + x1 * sn);
            }
        }
      } else {
        const int kh = (colb - NHEAD * HD - KVH * HD) >> 6;
#pragma unroll
        for (int nt = 0; nt < 4; ++nt) {
          const int d = nt * 16 + c;
#pragma unroll
          for (int mt = 0; mt < 4; ++mt) {
            const int sr = m0 + wm + mt * 16 + quad * 4;
            bf16x4 pv;
#pragma unroll
            for (int reg = 0; reg < 4; ++reg) pv[reg] = (bf16_t)acc[mt][nt][reg];
            *(bf16x4*)&vt2[((size_t)kh * HD + d) * S_LEN + sr] = pv;
          }
        }
      }
    }
  }
}

// ---------------- split-K MFMA flash (KVBLK=32) ----------------
// bpermute P redistribution (R14), chunked decomposition (R15), 32-key tiles
// double-buffered in 16KB LDS (R17/R18): Ks[2][32x64] 128B rows (XOR c&7),
// Vs[2][64x32] 64B rows (XOR c&3). (256,4): VGPR cap 128 >> live ~95.
__global__ __launch_bounds__(256, 4) void flash_split(const bf16_t* __restrict__ qb,
                                                      const bf16_t* __restrict__ kt,
                                                      const bf16_t* __restrict__ vt2,
                                                      float* __restrict__ pbuf,
                                                      bf16_t* __restrict__ attn) {
  __shared__ __align__(16) bf16_t Ks[2][32 * 64];
  __shared__ __align__(16) bf16_t Vs[2][64 * 32];

  const int tid  = threadIdx.x;
  const int lane = tid & 63;
  const int w    = tid >> 6;
  const int e    = (int)gridDim.x - 1 - (int)blockIdx.x;   // long chunks first
  const int kh   = e / NE_PER_KH;
  const int j    = e - kh * NE_PER_KH;

  int qt, chunk, nch;
  if (j < 8) {
    qt = j; chunk = 0; nch = 1;
  } else {
    int j2 = j - 8;
    qt = 8;
    for (;;) {
      nch = (qt + 8) >> 3;          // ceil((qt+1)/8)
      if (j2 < nch) { chunk = j2; break; }
      j2 -= nch; ++qt;
    }
  }
  const int T       = qt + 1;       // 32-key tiles
  const int t_begin = (chunk * T) / nch;
  const int t_end   = ((chunk + 1) * T) / nch;

  const int s0    = qt * 32;
  const int h     = kh * 4 + w;
  const int c     = lane & 15;
  const int quad  = lane >> 4;

  // loop-invariant bpermute source-lane indices (bytes)
  const int idx0 = (c + (quad & 1) * 32) * 4;
  const int idx1 = idx0 + 64;
  const bool hiY = quad >= 2;

  bf16x8 qf[2][2];
#pragma unroll
  for (int rf = 0; rf < 2; ++rf)
#pragma unroll
    for (int ks = 0; ks < 2; ++ks)
      qf[rf][ks] = *(const bf16x8*)(qb + (size_t)(s0 + rf * 16 + c) * H_DIM + h * HD + ks * 32 + quad * 8);

  f32x4 acc[2][4] = {};
  float lsum[2] = {0.f, 0.f};

  const bf16_t* kbase = kt + (size_t)kh * S_LEN * HD;
  const bf16_t* vbase = vt2 + (size_t)kh * HD * S_LEN;

  // staging: 256 16B chunks each for K and V per tile; thread tid owns chunk tid.
  // K: row = tid>>3 (32 rows x 128B), src chunk = (tid&7)^(row&7).
  // V: row d = tid>>2 (64 rows x 64B),  src chunk = (tid&3)^(d&3).
  const int krow = tid >> 3;
  const int kkc  = (tid & 7) ^ (krow & 7);
  const int vrow = tid >> 2;
  const int vkc  = (tid & 3) ^ (vrow & 3);
  const int sbase = w * 64 * 8;   // wave-uniform element base (lane*16B auto)

  auto stage = [&](int buf, int tile) {
    const int t0 = tile * 32;
    async_copy16(&Ks[buf][sbase], kbase + (size_t)(t0 + krow) * HD + kkc * 8);
    async_copy16(&Vs[buf][sbase], vbase + (size_t)vrow * S_LEN + t0 + vkc * 8);
  };

  stage(0, t_begin);
  int buf = 0;
  for (int tile = t_begin; tile < t_end; ++tile) {
    const int t0 = tile * 32;
    asm volatile("s_waitcnt vmcnt(0)" ::: "memory");
    __builtin_amdgcn_s_barrier();
    if (tile + 1 < t_end) stage(buf ^ 1, tile + 1);

    const bool masked = (tile == T - 1);

    unsigned pw[2][2][2];   // [rf][kt2][word]
#pragma unroll
    for (int kt2 = 0; kt2 < 2; ++kt2) {
      bf16x8 kf0 = *(const bf16x8*)&Ks[buf][((kt2 * 16 + c) * 8 + ((quad) ^ (c & 7))) * 8];
      bf16x8 kf1 = *(const bf16x8*)&Ks[buf][((kt2 * 16 + c) * 8 + ((4 + quad) ^ (c & 7))) * 8];
#pragma unroll
      for (int rf = 0; rf < 2; ++rf) {
        f32x4 st = {};
        __builtin_amdgcn_s_setprio(1);
        st = __builtin_amdgcn_mfma_f32_16x16x32_bf16(kf0, qf[rf][0], st, 0, 0, 0);
        st = __builtin_amdgcn_mfma_f32_16x16x32_bf16(kf1, qf[rf][1], st, 0, 0, 0);
        __builtin_amdgcn_s_setprio(0);
        const int row = s0 + rf * 16 + c;
        bf16x4 pk;
#pragma unroll
        for (int reg = 0; reg < 4; ++reg) {
          const int key = t0 + kt2 * 16 + quad * 4 + reg;
          float p = __builtin_amdgcn_exp2f(fmaf(st[reg], 1.44269504f, -11.54156036f));
          if (masked && key > row) p = 0.f;
          pk[reg] = (bf16_t)p;
          lsum[rf] += p;
        }
        u32x2 pv2 = __builtin_bit_cast(u32x2, pk);
        pw[rf][kt2][0] = pv2.x;
        pw[rf][kt2][1] = pv2.y;
      }
    }

    bf16x8 vf[4];
#pragma unroll
    for (int dt = 0; dt < 4; ++dt)
      vf[dt] = *(const bf16x8*)&Vs[buf][((dt * 16 + c) * 4 + (quad ^ (c & 3))) * 8];

#pragma unroll
    for (int rf = 0; rf < 2; ++rf) {
      int lo, hi;
      u32x4 fwv;
      lo = __builtin_amdgcn_ds_bpermute(idx0, (int)pw[rf][0][0]);
      hi = __builtin_amdgcn_ds_bpermute(idx0, (int)pw[rf][1][0]);
      fwv.x = hiY ? (unsigned)hi : (unsigned)lo;
      lo = __builtin_amdgcn_ds_bpermute(idx0, (int)pw[rf][0][1]);
      hi = __builtin_amdgcn_ds_bpermute(idx0, (int)pw[rf][1][1]);
      fwv.y = hiY ? (unsigned)hi : (unsigned)lo;
      lo = __builtin_amdgcn_ds_bpermute(idx1, (int)pw[rf][0][0]);
      hi = __builtin_amdgcn_ds_bpermute(idx1, (int)pw[rf][1][0]);
      fwv.z = hiY ? (unsigned)hi : (unsigned)lo;
      lo = __builtin_amdgcn_ds_bpermute(idx1, (int)pw[rf][0][1]);
      hi = __builtin_amdgcn_ds_bpermute(idx1, (int)pw[rf][1][1]);
      fwv.w = hiY ? (unsigned)hi : (unsigned)lo;
      bf16x8 pa = __builtin_bit_cast(bf16x8, fwv);
      __builtin_amdgcn_s_setprio(1);
#pragma unroll
      for (int dt = 0; dt < 4; ++dt)
        acc[rf][dt] = __builtin_amdgcn_mfma_f32_16x16x32_bf16(pa, vf[dt], acc[rf][dt], 0, 0, 0);
      __builtin_amdgcn_s_setprio(0);
    }
    buf ^= 1;
  }

#pragma unroll
  for (int rf = 0; rf < 2; ++rf) {
    lsum[rf] += __shfl_xor(lsum[rf], 16);
    lsum[rf] += __shfl_xor(lsum[rf], 32);
  }

  __syncthreads();   // all Ks readers done before reusing Ks as lbuf
  if (j < 8) {
    float* lbuf = (float*)&Ks[0][0] + w * 32;
#pragma unroll
    for (int rf = 0; rf < 2; ++rf) lbuf[rf * 16 + c] = lsum[rf];
    asm volatile("s_waitcnt lgkmcnt(0)" ::: "memory");
#pragma unroll
    for (int rf = 0; rf < 2; ++rf)
#pragma unroll
      for (int reg = 0; reg < 4; ++reg) {
        const float inv = 1.0f / lbuf[rf * 16 + quad * 4 + reg];
        const int row = s0 + rf * 16 + quad * 4 + reg;
#pragma unroll
        for (int dt = 0; dt < 4; ++dt)
          attn[(size_t)row * H_DIM + h * HD + dt * 16 + c] = (bf16_t)(acc[rf][dt][reg] * inv);
      }
  } else {
    const int slot = kh * NSPLIT_PER_KH + (j - 8);
    char* ent = (char*)pbuf + (size_t)slot * ENT_BYTES;
    bf16_t* eo = (bf16_t*)ent;
    float*  el = (float*)(ent + 16384);
#pragma unroll
    for (int rf = 0; rf < 2; ++rf) {
#pragma unroll
      for (int dt = 0; dt < 4; ++dt)
#pragma unroll
        for (int reg = 0; reg < 4; ++reg)
          eo[w * 2048 + (rf * 16 + quad * 4 + reg) * 64 + dt * 16 + c] = (bf16_t)acc[rf][dt][reg];
      el[w * 32 + rf * 16 + c] = lsum[rf];
    }
  }
}

// ---------------- reduce: sum bf16 partial chunks, normalize, write attn ----
// one block per (kh, qt>=8): 8*56 = 448 blocks. nch = ceil((qt+1)/8) —
// identical values to the R15 layout.
__global__ __launch_bounds__(256) void flash_reduce(const float* __restrict__ pbuf,
                                                    bf16_t* __restrict__ attn) {
  const int kh = blockIdx.x / 56;
  const int qt = 8 + (blockIdx.x % 56);

  int base = 0;
  for (int q = 8; q < qt; ++q) base += (q + 8) >> 3;
  const int nch = (qt + 8) >> 3;
  base += kh * NSPLIT_PER_KH;

  const int t   = threadIdx.x;
  const int h2  = t >> 6;
  const int row = (t >> 1) & 31;
  const int dh  = t & 1;

  f32x4 o[8] = {};
  float l = 0.f;
  for (int ci = 0; ci < nch; ++ci) {
    const char* ent = (const char*)pbuf + (size_t)(base + ci) * ENT_BYTES;
    const bf16_t* p = (const bf16_t*)ent + h2 * 2048 + row * 64 + dh * 32;
#pragma unroll
    for (int jj = 0; jj < 8; ++jj) {
      bf16x4 v = ((const bf16x4*)p)[jj];
      o[jj][0] += (float)v[0]; o[jj][1] += (float)v[1];
      o[jj][2] += (float)v[2]; o[jj][3] += (float)v[3];
    }
    l += ((const float*)(ent + 16384))[h2 * 32 + row];
  }
  const float inv = 1.0f / l;
  bf16_t* dst = attn + (size_t)(qt * 32 + row) * H_DIM + (kh * 4 + h2) * 64 + dh * 32;
#pragma unroll
  for (int jj = 0; jj < 8; ++jj) {
    bf16x4 ov;
    ov[0] = (bf16_t)(o[jj][0] * inv); ov[1] = (bf16_t)(o[jj][1] * inv);
    ov[2] = (bf16_t)(o[jj][2] * inv); ov[3] = (bf16_t)(o[jj][3] * inv);
    *(bf16x4*)(dst + jj * 4) = ov;
  }
}

// ---------------- launch ----------------
extern "C" void kernel_launch(void* const* d_in, const int* in_sizes, int n_in,
                              void* d_out, int out_size, void* d_ws, size_t ws_size,
                              hipStream_t stream) {
  const float* x     = (const float*)d_in[0];
  const float* w_qkv = (const float*)d_in[1];
  const float* w_o   = (const float*)d_in[2];
  float* out = (float*)d_out;

  char* ws = (char*)d_ws;
  const size_t OVERLAY = (size_t)1280 * 8320 * 4;  // 42.6 MB (pbuf needs 36.1MB)
  bf16_t* x_bf    = (bf16_t*)ws;
  bf16_t* wqkv_bf = (bf16_t*)(ws + (size_t)S_LEN * H_DIM * 2);
  float*  pbuf    = (float*)ws;
  size_t off = OVERLAY;
  bf16_t* wo_bf   = (bf16_t*)(ws + off); off += (size_t)H_DIM * H_DIM * 2;
  bf16_t* q_bf    = (bf16_t*)(ws + off); off += (size_t)S_LEN * H_DIM * 2;
  bf16_t* k_t     = (bf16_t*)(ws + off); off += (size_t)KVH * S_LEN * HD * 2;
  bf16_t* v_t2    = (bf16_t*)(ws + off); off += (size_t)KVH * S_LEN * HD * 2;
  bf16_t* attn    = (bf16_t*)(ws + off); off += (size_t)S_LEN * H_DIM * 2;

  const int ntot = (S_LEN * H_DIM + QKV_N * H_DIM + H_DIM * H_DIM) / 4;
  cast3_kernel<<<(ntot + 255) / 256, 256, 0, stream>>>(x, w_qkv, w_o, x_bf, wqkv_bf, wo_bf);

  gemm_sk<1><<<dim3(QKV_N / GBN, S_LEN / GBM), 512, 0, stream>>>(
      x_bf, wqkv_bf, nullptr, q_bf, k_t, v_t2, S_LEN, QKV_N, H_DIM);

  flash_split<<<8 * NE_PER_KH, 256, 0, stream>>>(q_bf, k_t, v_t2, pbuf, attn);
  flash_reduce<<<8 * 56, 256, 0, stream>>>(pbuf, attn);

  gemm_sk<0><<<dim3(H_DIM / GBN, S_LEN / GBM), 512, 0, stream>>>(
      attn, wo_bf, out, nullptr, nullptr, nullptr, S_LEN, H_DIM, H_DIM);
}

// Round 11
// 216.987 us; speedup vs baseline: 1.2767x; 1.0026x over previous
//
#include <hip/hip_runtime.h>

// Attention block: qkv proj -> RoPE -> causal GQA flash attention -> out proj.
// B=1, S=2048, H=2048, NH=32, KVH=8, D=64, G=4.
// R8:  gemm rework (8 waves, wave-pair split-K). flash ~49us.
// R15 (win, 49.5->45): <=4-tile chunks, 2304 blocks, bf16 partials.
// R16 (regressed): MFMA-ones lsum serial dep chain. Reverted.
// R17 (regressed): (256,6) spill. R18: (256,4) fixed -> 44.7us, flash
//      plateaued across 6 structural variants. VGPR 52, occ 30%.
// R19: (a) Vs bank-conflict fix: chunk pos = x ^ f(r), f(r)=(r+(r>>2))&3 --
//      old f(r)=r&3 made lanes c,c+4,c+8,c+12 hit one 4-bank group (4-way,
//      1.58x); new mapping is exactly 2-way (free). Conflict 3.19M -> ~2.2M.
//      (b) XCD-aware block swizzle in gemm_sk (T1): both grids %8==0 ->
//      bijective; contiguous tile ranges per XCD -> A-panel L2 locality.

typedef __bf16 bf16_t;
typedef __attribute__((ext_vector_type(8))) __bf16 bf16x8;
typedef __attribute__((ext_vector_type(4))) __bf16 bf16x4;
typedef __attribute__((ext_vector_type(4))) float f32x4;
typedef __attribute__((ext_vector_type(2))) unsigned int u32x2;
typedef __attribute__((ext_vector_type(4))) unsigned int u32x4;

#define S_LEN 2048
#define H_DIM 2048
#define NHEAD 32
#define KVH 8
#define HD 64
#define QKV_N 3072  // (NH + 2*KVH) * D

// split-K chunking: qt 0..7 direct (T=qt+1 <= 8 tiles of 32 keys);
// qt 8..63 split into ceil((qt+1)/8) chunks. Per kh: 8 direct + 280 split.
#define NE_PER_KH 288
#define NSPLIT_PER_KH 280
// partial entry: 4h*32r*64d bf16 (16384B) + 4h*32r lsum f32 (512B)
#define ENT_BYTES 16896

// ---------------- fused cast fp32 -> bf16 (x, w_qkv, w_o) ----------------
__global__ void cast3_kernel(const float* __restrict__ x, const float* __restrict__ wq,
                             const float* __restrict__ wo, bf16_t* __restrict__ xb,
                             bf16_t* __restrict__ wqb, bf16_t* __restrict__ wob) {
  int i = blockIdx.x * blockDim.x + threadIdx.x;
  const int n1 = S_LEN * H_DIM / 4, n2 = QKV_N * H_DIM / 4, n3 = H_DIM * H_DIM / 4;
  const float* src; bf16_t* dst; int j;
  if (i < n1)           { src = x;  dst = xb;  j = i; }
  else if (i < n1 + n2) { src = wq; dst = wqb; j = i - n1; }
  else if (i < n1 + n2 + n3) { src = wo; dst = wob; j = i - n1 - n2; }
  else return;
  float4 v = ((const float4*)src)[j];
  bf16x4 o;
  o.x = (bf16_t)v.x; o.y = (bf16_t)v.y; o.z = (bf16_t)v.z; o.w = (bf16_t)v.w;
  ((bf16x4*)dst)[j] = o;
}

// ---------------- async 16B global -> LDS ----------------
__device__ __forceinline__ void async_copy16(bf16_t* lds_base, const bf16_t* g) {
  __builtin_amdgcn_global_load_lds(
      (const __attribute__((address_space(1))) unsigned int*)g,
      (__attribute__((address_space(3))) unsigned int*)lds_base, 16, 0, 0);
}

// ---------------- GEMM: C[M,N] = A[M,K] * B[N,K]^T (bf16 in) ----------------
#define GBM 128
#define GBN 128

template <int EPI>
__global__ __launch_bounds__(512, 4) void gemm_sk(const bf16_t* __restrict__ A,
                                                  const bf16_t* __restrict__ B,
                                                  float* __restrict__ C,
                                                  bf16_t* __restrict__ qb,
                                                  bf16_t* __restrict__ ktp,
                                                  bf16_t* __restrict__ vt2,
                                                  int M, int N, int K) {
  __shared__ __align__(16) bf16_t As[2][GBM * 64];
  __shared__ __align__(16) bf16_t Bs[2][GBM * 64];

  const int tid  = threadIdx.x;
  const int lane = tid & 63;
  const int w    = tid >> 6;          // 0..7
  const int wq   = w & 3;             // pair id / subtile
  const int gw   = w >> 2;            // K32 group
  const int wm   = (wq >> 1) * 64;
  const int wn   = (wq & 1) * 64;
  const int c    = lane & 15;
  const int quad = lane >> 4;

  // XCD-aware block swizzle (T1): dispatch round-robins linear bid across 8
  // XCDs; remap so each XCD owns a contiguous tile range (A-panel L2 reuse).
  // Grids are 384 / 256 blocks -> %8==0 -> bijective.
  const int nwg = (int)(gridDim.x * gridDim.y);
  const int bid = (int)blockIdx.y * (int)gridDim.x + (int)blockIdx.x;
  const int swz = (bid & 7) * (nwg >> 3) + (bid >> 3);
  const int m0  = (swz / (int)gridDim.x) * GBM;
  const int n0  = (swz % (int)gridDim.x) * GBN;

  f32x4 acc[4][4] = {};

  const bf16_t* Ab = A + (size_t)m0 * K;
  const bf16_t* Bb = B + (size_t)n0 * K;

  int srow[2], skc[2], sb[2];
#pragma unroll
  for (int i = 0; i < 2; ++i) {
    int p = i * 512 + tid;
    srow[i] = p >> 3;
    skc[i]  = (p & 7) ^ (srow[i] & 7);
    sb[i]   = (i * 512 + w * 64) * 8;   // wave-uniform element base
  }

  auto stage = [&](int buf, int k0) {
#pragma unroll
    for (int i = 0; i < 2; ++i) {
      async_copy16(&As[buf][sb[i]], Ab + (size_t)srow[i] * K + k0 + skc[i] * 8);
      async_copy16(&Bs[buf][sb[i]], Bb + (size_t)srow[i] * K + k0 + skc[i] * 8);
    }
  };

  auto compute = [&](int buf) {
    bf16x8 af[4], bfr[4];
#pragma unroll
    for (int mt = 0; mt < 4; ++mt) {
      int row = wm + mt * 16 + c;
      af[mt] = *(const bf16x8*)&As[buf][(row * 8 + ((gw * 4 + quad) ^ (row & 7))) * 8];
    }
#pragma unroll
    for (int nt = 0; nt < 4; ++nt) {
      int rowb = wn + nt * 16 + c;
      bfr[nt] = *(const bf16x8*)&Bs[buf][(rowb * 8 + ((gw * 4 + quad) ^ (rowb & 7))) * 8];
    }
#pragma unroll
    for (int mt = 0; mt < 4; ++mt)
#pragma unroll
      for (int nt = 0; nt < 4; ++nt)
        acc[mt][nt] = __builtin_amdgcn_mfma_f32_16x16x32_bf16(af[mt], bfr[nt], acc[mt][nt], 0, 0, 0);
  };

  const int NI = K >> 6;   // BK=64 iterations
  stage(0, 0);
  int buf = 0;
  for (int it = 0; it < NI; ++it) {
    asm volatile("s_waitcnt vmcnt(0)" ::: "memory");
    __builtin_amdgcn_s_barrier();
    if (it + 1 < NI) stage(buf ^ 1, (it + 1) << 6);
    compute(buf);
    buf ^= 1;
  }

  __syncthreads();
  float* xch = (float*)&As[0][0];
  if (gw == 1) {
#pragma unroll
    for (int t16 = 0; t16 < 16; ++t16)
      *(f32x4*)&xch[wq * 4096 + (t16 * 64 + lane) * 4] = acc[t16 >> 2][t16 & 3];
  }
  __syncthreads();
  if (gw == 0) {
#pragma unroll
    for (int t16 = 0; t16 < 16; ++t16) {
      f32x4 o = *(const f32x4*)&xch[wq * 4096 + (t16 * 64 + lane) * 4];
      acc[t16 >> 2][t16 & 3] += o;
    }

    if (EPI == 0) {
#pragma unroll
      for (int mt = 0; mt < 4; ++mt)
#pragma unroll
        for (int nt = 0; nt < 4; ++nt)
#pragma unroll
          for (int reg = 0; reg < 4; ++reg) {
            int row = m0 + wm + mt * 16 + quad * 4 + reg;
            int col = n0 + wn + nt * 16 + c;
            C[(size_t)row * N + col] = acc[mt][nt][reg];
          }
    } else {
      const int colb = n0 + wn;
      if (colb < NHEAD * HD) {
        const int h = colb >> 6;
#pragma unroll
        for (int nt = 0; nt < 2; ++nt) {
          const int i = nt * 16 + c;
          const float invf = __expf(-(float)i * (9.210340371976184f / 32.0f));
#pragma unroll
          for (int mt = 0; mt < 4; ++mt)
#pragma unroll
            for (int reg = 0; reg < 4; ++reg) {
              const int s = m0 + wm + mt * 16 + quad * 4 + reg;
              float sn, cs;
              __sincosf((float)s * invf, &sn, &cs);
              const float x1 = acc[mt][nt][reg], x2 = acc[mt][nt + 2][reg];
              bf16_t* q = qb + (size_t)s * H_DIM + h * HD;
              q[i]      = (bf16_t)((x1 * cs - x2 * sn) * 0.125f);
              q[i + 32] = (bf16_t)((x2 * cs + x1 * sn) * 0.125f);
            }
        }
      } else if (colb < NHEAD * HD + KVH * HD) {
        const int kh = (colb - NHEAD * HD) >> 6;
#pragma unroll
        for (int nt = 0; nt < 2; ++nt) {
          const int i = nt * 16 + c;
          const float invf = __expf(-(float)i * (9.210340371976184f / 32.0f));
#pragma unroll
          for (int mt = 0; mt < 4; ++mt)
#pragma unroll
            for (int reg = 0; reg < 4; ++reg) {
              const int s = m0 + wm + mt * 16 + quad * 4 + reg;
              float sn, cs;
              __sincosf((float)s * invf, &sn, &cs);
              const float x1 = acc[mt][nt][reg], x2 = acc[mt][nt + 2][reg];
              bf16_t* kd = ktp + ((size_t)kh * S_LEN + s) * HD;
              kd[i]      = (bf16_t)(x1 * cs - x2 * sn);
              kd[i + 32] = (bf16_t)(x2 * cs + x1 * sn);
            }
        }
      } else {
        const int kh = (colb - NHEAD * HD - KVH * HD) >> 6;
#pragma unroll
        for (int nt = 0; nt < 4; ++nt) {
          const int d = nt * 16 + c;
#pragma unroll
          for (int mt = 0; mt < 4; ++mt) {
            const int sr = m0 + wm + mt * 16 + quad * 4;
            bf16x4 pv;
#pragma unroll
            for (int reg = 0; reg < 4; ++reg) pv[reg] = (bf16_t)acc[mt][nt][reg];
            *(bf16x4*)&vt2[((size_t)kh * HD + d) * S_LEN + sr] = pv;
          }
        }
      }
    }
  }
}

// ---------------- split-K MFMA flash (KVBLK=32) ----------------
// bpermute P redistribution (R14), chunked decomposition (R15), 32-key tiles
// double-buffered in 16KB LDS (R18). Vs chunk swizzle f(r)=(r+(r>>2))&3 (R19)
// -> exactly 2-way bank aliasing (free) instead of 4-way.
__global__ __launch_bounds__(256, 4) void flash_split(const bf16_t* __restrict__ qb,
                                                      const bf16_t* __restrict__ kt,
                                                      const bf16_t* __restrict__ vt2,
                                                      float* __restrict__ pbuf,
                                                      bf16_t* __restrict__ attn) {
  __shared__ __align__(16) bf16_t Ks[2][32 * 64];
  __shared__ __align__(16) bf16_t Vs[2][64 * 32];

  const int tid  = threadIdx.x;
  const int lane = tid & 63;
  const int w    = tid >> 6;
  const int e    = (int)gridDim.x - 1 - (int)blockIdx.x;   // long chunks first
  const int kh   = e / NE_PER_KH;
  const int j    = e - kh * NE_PER_KH;

  int qt, chunk, nch;
  if (j < 8) {
    qt = j; chunk = 0; nch = 1;
  } else {
    int j2 = j - 8;
    qt = 8;
    for (;;) {
      nch = (qt + 8) >> 3;          // ceil((qt+1)/8)
      if (j2 < nch) { chunk = j2; break; }
      j2 -= nch; ++qt;
    }
  }
  const int T       = qt + 1;       // 32-key tiles
  const int t_begin = (chunk * T) / nch;
  const int t_end   = ((chunk + 1) * T) / nch;

  const int s0    = qt * 32;
  const int h     = kh * 4 + w;
  const int c     = lane & 15;
  const int quad  = lane >> 4;

  // loop-invariant bpermute source-lane indices (bytes)
  const int idx0 = (c + (quad & 1) * 32) * 4;
  const int idx1 = idx0 + 64;
  const bool hiY = quad >= 2;

  bf16x8 qf[2][2];
#pragma unroll
  for (int rf = 0; rf < 2; ++rf)
#pragma unroll
    for (int ks = 0; ks < 2; ++ks)
      qf[rf][ks] = *(const bf16x8*)(qb + (size_t)(s0 + rf * 16 + c) * H_DIM + h * HD + ks * 32 + quad * 8);

  f32x4 acc[2][4] = {};
  float lsum[2] = {0.f, 0.f};

  const bf16_t* kbase = kt + (size_t)kh * S_LEN * HD;
  const bf16_t* vbase = vt2 + (size_t)kh * HD * S_LEN;

  // staging: 256 16B chunks each for K and V per tile; thread tid owns chunk tid.
  // K: row = tid>>3 (32 rows x 128B), src chunk = (tid&7)^(row&7).
  // V: row d = tid>>2 (64 rows x 64B),  src chunk = (tid&3)^f(d), f(d)=(d+(d>>2))&3.
  const int krow = tid >> 3;
  const int kkc  = (tid & 7) ^ (krow & 7);
  const int vrow = tid >> 2;
  const int vkc  = (tid & 3) ^ ((vrow + (vrow >> 2)) & 3);
  const int sbase = w * 64 * 8;   // wave-uniform element base (lane*16B auto)

  auto stage = [&](int buf, int tile) {
    const int t0 = tile * 32;
    async_copy16(&Ks[buf][sbase], kbase + (size_t)(t0 + krow) * HD + kkc * 8);
    async_copy16(&Vs[buf][sbase], vbase + (size_t)vrow * S_LEN + t0 + vkc * 8);
  };

  stage(0, t_begin);
  int buf = 0;
  for (int tile = t_begin; tile < t_end; ++tile) {
    const int t0 = tile * 32;
    asm volatile("s_waitcnt vmcnt(0)" ::: "memory");
    __builtin_amdgcn_s_barrier();
    if (tile + 1 < t_end) stage(buf ^ 1, tile + 1);

    const bool masked = (tile == T - 1);

    unsigned pw[2][2][2];   // [rf][kt2][word]
#pragma unroll
    for (int kt2 = 0; kt2 < 2; ++kt2) {
      bf16x8 kf0 = *(const bf16x8*)&Ks[buf][((kt2 * 16 + c) * 8 + ((quad) ^ (c & 7))) * 8];
      bf16x8 kf1 = *(const bf16x8*)&Ks[buf][((kt2 * 16 + c) * 8 + ((4 + quad) ^ (c & 7))) * 8];
#pragma unroll
      for (int rf = 0; rf < 2; ++rf) {
        f32x4 st = {};
        __builtin_amdgcn_s_setprio(1);
        st = __builtin_amdgcn_mfma_f32_16x16x32_bf16(kf0, qf[rf][0], st, 0, 0, 0);
        st = __builtin_amdgcn_mfma_f32_16x16x32_bf16(kf1, qf[rf][1], st, 0, 0, 0);
        __builtin_amdgcn_s_setprio(0);
        const int row = s0 + rf * 16 + c;
        bf16x4 pk;
#pragma unroll
        for (int reg = 0; reg < 4; ++reg) {
          const int key = t0 + kt2 * 16 + quad * 4 + reg;
          float p = __builtin_amdgcn_exp2f(fmaf(st[reg], 1.44269504f, -11.54156036f));
          if (masked && key > row) p = 0.f;
          pk[reg] = (bf16_t)p;
          lsum[rf] += p;
        }
        u32x2 pv2 = __builtin_bit_cast(u32x2, pk);
        pw[rf][kt2][0] = pv2.x;
        pw[rf][kt2][1] = pv2.y;
      }
    }

    bf16x8 vf[4];
#pragma unroll
    for (int dt = 0; dt < 4; ++dt)
      vf[dt] = *(const bf16x8*)&Vs[buf][((dt * 16 + c) * 4 + (quad ^ ((c + (c >> 2)) & 3))) * 8];

#pragma unroll
    for (int rf = 0; rf < 2; ++rf) {
      int lo, hi;
      u32x4 fwv;
      lo = __builtin_amdgcn_ds_bpermute(idx0, (int)pw[rf][0][0]);
      hi = __builtin_amdgcn_ds_bpermute(idx0, (int)pw[rf][1][0]);
      fwv.x = hiY ? (unsigned)hi : (unsigned)lo;
      lo = __builtin_amdgcn_ds_bpermute(idx0, (int)pw[rf][0][1]);
      hi = __builtin_amdgcn_ds_bpermute(idx0, (int)pw[rf][1][1]);
      fwv.y = hiY ? (unsigned)hi : (unsigned)lo;
      lo = __builtin_amdgcn_ds_bpermute(idx1, (int)pw[rf][0][0]);
      hi = __builtin_amdgcn_ds_bpermute(idx1, (int)pw[rf][1][0]);
      fwv.z = hiY ? (unsigned)hi : (unsigned)lo;
      lo = __builtin_amdgcn_ds_bpermute(idx1, (int)pw[rf][0][1]);
      hi = __builtin_amdgcn_ds_bpermute(idx1, (int)pw[rf][1][1]);
      fwv.w = hiY ? (unsigned)hi : (unsigned)lo;
      bf16x8 pa = __builtin_bit_cast(bf16x8, fwv);
      __builtin_amdgcn_s_setprio(1);
#pragma unroll
      for (int dt = 0; dt < 4; ++dt)
        acc[rf][dt] = __builtin_amdgcn_mfma_f32_16x16x32_bf16(pa, vf[dt], acc[rf][dt], 0, 0, 0);
      __builtin_amdgcn_s_setprio(0);
    }
    buf ^= 1;
  }

#pragma unroll
  for (int rf = 0; rf < 2; ++rf) {
    lsum[rf] += __shfl_xor(lsum[rf], 16);
    lsum[rf] += __shfl_xor(lsum[rf], 32);
  }

  __syncthreads();   // all Ks readers done before reusing Ks as lbuf
  if (j < 8) {
    float* lbuf = (float*)&Ks[0][0] + w * 32;
#pragma unroll
    for (int rf = 0; rf < 2; ++rf) lbuf[rf * 16 + c] = lsum[rf];
    asm volatile("s_waitcnt lgkmcnt(0)" ::: "memory");
#pragma unroll
    for (int rf = 0; rf < 2; ++rf)
#pragma unroll
      for (int reg = 0; reg < 4; ++reg) {
        const float inv = 1.0f / lbuf[rf * 16 + quad * 4 + reg];
        const int row = s0 + rf * 16 + quad * 4 + reg;
#pragma unroll
        for (int dt = 0; dt < 4; ++dt)
          attn[(size_t)row * H_DIM + h * HD + dt * 16 + c] = (bf16_t)(acc[rf][dt][reg] * inv);
      }
  } else {
    const int slot = kh * NSPLIT_PER_KH + (j - 8);
    char* ent = (char*)pbuf + (size_t)slot * ENT_BYTES;
    bf16_t* eo = (bf16_t*)ent;
    float*  el = (float*)(ent + 16384);
#pragma unroll
    for (int rf = 0; rf < 2; ++rf) {
#pragma unroll
      for (int dt = 0; dt < 4; ++dt)
#pragma unroll
        for (int reg = 0; reg < 4; ++reg)
          eo[w * 2048 + (rf * 16 + quad * 4 + reg) * 64 + dt * 16 + c] = (bf16_t)acc[rf][dt][reg];
      el[w * 32 + rf * 16 + c] = lsum[rf];
    }
  }
}

// ---------------- reduce: sum bf16 partial chunks, normalize, write attn ----
// one block per (kh, qt>=8): 8*56 = 448 blocks. nch = ceil((qt+1)/8).
__global__ __launch_bounds__(256) void flash_reduce(const float* __restrict__ pbuf,
                                                    bf16_t* __restrict__ attn) {
  const int kh = blockIdx.x / 56;
  const int qt = 8 + (blockIdx.x % 56);

  int base = 0;
  for (int q = 8; q < qt; ++q) base += (q + 8) >> 3;
  const int nch = (qt + 8) >> 3;
  base += kh * NSPLIT_PER_KH;

  const int t   = threadIdx.x;
  const int h2  = t >> 6;
  const int row = (t >> 1) & 31;
  const int dh  = t & 1;

  f32x4 o[8] = {};
  float l = 0.f;
  for (int ci = 0; ci < nch; ++ci) {
    const char* ent = (const char*)pbuf + (size_t)(base + ci) * ENT_BYTES;
    const bf16_t* p = (const bf16_t*)ent + h2 * 2048 + row * 64 + dh * 32;
#pragma unroll
    for (int jj = 0; jj < 8; ++jj) {
      bf16x4 v = ((const bf16x4*)p)[jj];
      o[jj][0] += (float)v[0]; o[jj][1] += (float)v[1];
      o[jj][2] += (float)v[2]; o[jj][3] += (float)v[3];
    }
    l += ((const float*)(ent + 16384))[h2 * 32 + row];
  }
  const float inv = 1.0f / l;
  bf16_t* dst = attn + (size_t)(qt * 32 + row) * H_DIM + (kh * 4 + h2) * 64 + dh * 32;
#pragma unroll
  for (int jj = 0; jj < 8; ++jj) {
    bf16x4 ov;
    ov[0] = (bf16_t)(o[jj][0] * inv); ov[1] = (bf16_t)(o[jj][1] * inv);
    ov[2] = (bf16_t)(o[jj][2] * inv); ov[3] = (bf16_t)(o[jj][3] * inv);
    *(bf16x4*)(dst + jj * 4) = ov;
  }
}

// ---------------- launch ----------------
extern "C" void kernel_launch(void* const* d_in, const int* in_sizes, int n_in,
                              void* d_out, int out_size, void* d_ws, size_t ws_size,
                              hipStream_t stream) {
  const float* x     = (const float*)d_in[0];
  const float* w_qkv = (const float*)d_in[1];
  const float* w_o   = (const float*)d_in[2];
  float* out = (float*)d_out;

  char* ws = (char*)d_ws;
  const size_t OVERLAY = (size_t)1280 * 8320 * 4;  // 42.6 MB (pbuf needs 36.1MB)
  bf16_t* x_bf    = (bf16_t*)ws;
  bf16_t* wqkv_bf = (bf16_t*)(ws + (size_t)S_LEN * H_DIM * 2);
  float*  pbuf    = (float*)ws;
  size_t off = OVERLAY;
  bf16_t* wo_bf   = (bf16_t*)(ws + off); off += (size_t)H_DIM * H_DIM * 2;
  bf16_t* q_bf    = (bf16_t*)(ws + off); off += (size_t)S_LEN * H_DIM * 2;
  bf16_t* k_t     = (bf16_t*)(ws + off); off += (size_t)KVH * S_LEN * HD * 2;
  bf16_t* v_t2    = (bf16_t*)(ws + off); off += (size_t)KVH * S_LEN * HD * 2;
  bf16_t* attn    = (bf16_t*)(ws + off); off += (size_t)S_LEN * H_DIM * 2;

  const int ntot = (S_LEN * H_DIM + QKV_N * H_DIM + H_DIM * H_DIM) / 4;
  cast3_kernel<<<(ntot + 255) / 256, 256, 0, stream>>>(x, w_qkv, w_o, x_bf, wqkv_bf, wo_bf);

  gemm_sk<1><<<dim3(QKV_N / GBN, S_LEN / GBM), 512, 0, stream>>>(
      x_bf, wqkv_bf, nullptr, q_bf, k_t, v_t2, S_LEN, QKV_N, H_DIM);

  flash_split<<<8 * NE_PER_KH, 256, 0, stream>>>(q_bf, k_t, v_t2, pbuf, attn);
  flash_reduce<<<8 * 56, 256, 0, stream>>>(pbuf, attn);

  gemm_sk<0><<<dim3(H_DIM / GBN, S_LEN / GBM), 512, 0, stream>>>(
      attn, wo_bf, out, nullptr, nullptr, nullptr, S_LEN, H_DIM, H_DIM);
}

// Round 13
// 204.980 us; speedup vs baseline: 1.3515x; 1.0586x over previous
//
#include <hip/hip_runtime.h>

// Attention block: qkv proj -> RoPE -> causal GQA flash attention -> out proj.
// B=1, S=2048, H=2048, NH=32, KVH=8, D=64, G=4.
// R15/R18/R19: flash at ~45us (chunked split-K, KVBLK=32, 16KB LDS dbuf).
// R20 (FAILED absmax 0.686): GBM 128->64 GEMM rework was structurally right,
//      but the partial-combine exchange assumed As precedes Bs in LDS. LLVM
//      allocates LDS by decreasing (alignment, size): Bs(32KB) > As(16KB) put
//      As at +32KB, so subtile wq=2,3 exchange writes landed OOB (dropped) ->
//      rows 32-63 lost their gw=1 K-half. Magnitude matched (~0.7 = half-dot).
// R21: single explicitly-carved smem array (As at 0, Bs at 16KB, xch spans
//      [0,32KB) of 48KB -- layout guaranteed). RULE: cross-array LDS
//      addressing requires a manually carved single array.

typedef __bf16 bf16_t;
typedef __attribute__((ext_vector_type(8))) __bf16 bf16x8;
typedef __attribute__((ext_vector_type(4))) __bf16 bf16x4;
typedef __attribute__((ext_vector_type(4))) float f32x4;
typedef __attribute__((ext_vector_type(2))) unsigned int u32x2;
typedef __attribute__((ext_vector_type(4))) unsigned int u32x4;

#define S_LEN 2048
#define H_DIM 2048
#define NHEAD 32
#define KVH 8
#define HD 64
#define QKV_N 3072  // (NH + 2*KVH) * D

// split-K chunking: qt 0..7 direct (T=qt+1 <= 8 tiles of 32 keys);
// qt 8..63 split into ceil((qt+1)/8) chunks. Per kh: 8 direct + 280 split.
#define NE_PER_KH 288
#define NSPLIT_PER_KH 280
// partial entry: 4h*32r*64d bf16 (16384B) + 4h*32r lsum f32 (512B)
#define ENT_BYTES 16896

// ---------------- fused cast fp32 -> bf16 (x, w_qkv, w_o) ----------------
__global__ void cast3_kernel(const float* __restrict__ x, const float* __restrict__ wq,
                             const float* __restrict__ wo, bf16_t* __restrict__ xb,
                             bf16_t* __restrict__ wqb, bf16_t* __restrict__ wob) {
  int i = blockIdx.x * blockDim.x + threadIdx.x;
  const int n1 = S_LEN * H_DIM / 4, n2 = QKV_N * H_DIM / 4, n3 = H_DIM * H_DIM / 4;
  const float* src; bf16_t* dst; int j;
  if (i < n1)           { src = x;  dst = xb;  j = i; }
  else if (i < n1 + n2) { src = wq; dst = wqb; j = i - n1; }
  else if (i < n1 + n2 + n3) { src = wo; dst = wob; j = i - n1 - n2; }
  else return;
  float4 v = ((const float4*)src)[j];
  bf16x4 o;
  o.x = (bf16_t)v.x; o.y = (bf16_t)v.y; o.z = (bf16_t)v.z; o.w = (bf16_t)v.w;
  ((bf16x4*)dst)[j] = o;
}

// ---------------- async 16B global -> LDS ----------------
__device__ __forceinline__ void async_copy16(bf16_t* lds_base, const bf16_t* g) {
  __builtin_amdgcn_global_load_lds(
      (const __attribute__((address_space(1))) unsigned int*)g,
      (__attribute__((address_space(3))) unsigned int*)lds_base, 16, 0, 0);
}

// ---------------- GEMM: C[M,N] = A[M,K] * B[N,K]^T (bf16 in) ----------------
// 64x128 tile (R20/R21), 512 threads = 8 waves. Wave wq owns a 32x64
// C-subtile (2x2 grid); gw=w>>2 processes K32-half gw of each BK=64 iter.
// Double-buffered async staging, 1 raw barrier + vmcnt(0) per iter.
// EPI=0: C fp32 plain.  EPI=1: fused qkv epilogue (RoPE q/k, V transpose).
#define GBM 64
#define GBN 128

template <int EPI>
__global__ __launch_bounds__(512, 4) void gemm_sk(const bf16_t* __restrict__ A,
                                                  const bf16_t* __restrict__ B,
                                                  float* __restrict__ C,
                                                  bf16_t* __restrict__ qb,
                                                  bf16_t* __restrict__ ktp,
                                                  bf16_t* __restrict__ vt2,
                                                  int M, int N, int K) {
  // single carved LDS block: As[2] at 0 (16KB), Bs[2] at +16KB (32KB).
  // xch (32KB) spans [0,32KB) -- layout explicit, no allocator assumptions.
  __shared__ __align__(16) bf16_t smem[(2 * GBM + 2 * GBN) * 64];
  bf16_t (*As)[GBM * 64] = (bf16_t(*)[GBM * 64])smem;
  bf16_t (*Bs)[GBN * 64] = (bf16_t(*)[GBN * 64])(smem + 2 * GBM * 64);

  const int tid  = threadIdx.x;
  const int lane = tid & 63;
  const int w    = tid >> 6;          // 0..7
  const int wq   = w & 3;             // subtile id
  const int gw   = w >> 2;            // K32 group
  const int wm   = (wq >> 1) * 32;
  const int wn   = (wq & 1) * 64;
  const int c    = lane & 15;
  const int quad = lane >> 4;

  // XCD-aware block swizzle (T1): grids 768/512 are %8==0 -> bijective.
  const int nwg = (int)(gridDim.x * gridDim.y);
  const int bid = (int)blockIdx.y * (int)gridDim.x + (int)blockIdx.x;
  const int swz = (bid & 7) * (nwg >> 3) + (bid >> 3);
  const int m0  = (swz / (int)gridDim.x) * GBM;
  const int n0  = (swz % (int)gridDim.x) * GBN;

  f32x4 acc[2][4] = {};

  const bf16_t* Ab = A + (size_t)m0 * K;
  const bf16_t* Bb = B + (size_t)n0 * K;

  // staging per BK=64 iter: A = 512 chunks (64 rows x 8), B = 1024 chunks
  // (128 rows x 8). chunk p: row=p>>3, kc=(p&7)^(row&7).
  const int arow = tid >> 3;
  const int akc  = (tid & 7) ^ (arow & 7);
  const int asb  = (w * 64) * 8;
  int brow[2], bkc[2], bsb[2];
#pragma unroll
  for (int i = 0; i < 2; ++i) {
    int p = i * 512 + tid;
    brow[i] = p >> 3;
    bkc[i]  = (p & 7) ^ (brow[i] & 7);
    bsb[i]  = (i * 512 + w * 64) * 8;
  }

  auto stage = [&](int buf, int k0) {
    async_copy16(&As[buf][asb], Ab + (size_t)arow * K + k0 + akc * 8);
#pragma unroll
    for (int i = 0; i < 2; ++i)
      async_copy16(&Bs[buf][bsb[i]], Bb + (size_t)brow[i] * K + k0 + bkc[i] * 8);
  };

  auto compute = [&](int buf) {
    bf16x8 af[2], bfr[4];
#pragma unroll
    for (int mt = 0; mt < 2; ++mt) {
      int row = wm + mt * 16 + c;
      af[mt] = *(const bf16x8*)&As[buf][(row * 8 + ((gw * 4 + quad) ^ (row & 7))) * 8];
    }
#pragma unroll
    for (int nt = 0; nt < 4; ++nt) {
      int rowb = wn + nt * 16 + c;
      bfr[nt] = *(const bf16x8*)&Bs[buf][(rowb * 8 + ((gw * 4 + quad) ^ (rowb & 7))) * 8];
    }
#pragma unroll
    for (int mt = 0; mt < 2; ++mt)
#pragma unroll
      for (int nt = 0; nt < 4; ++nt)
        acc[mt][nt] = __builtin_amdgcn_mfma_f32_16x16x32_bf16(af[mt], bfr[nt], acc[mt][nt], 0, 0, 0);
  };

  const int NI = K >> 6;   // BK=64 iterations
  stage(0, 0);
  int buf = 0;
  for (int it = 0; it < NI; ++it) {
    asm volatile("s_waitcnt vmcnt(0)" ::: "memory");
    __builtin_amdgcn_s_barrier();
    if (it + 1 < NI) stage(buf ^ 1, (it + 1) << 6);
    compute(buf);
    buf ^= 1;
  }

  // combine wave-pair partials through LDS: 4 subtiles x 8KB = 32KB over the
  // explicitly carved smem (dead staging data) -- guaranteed in-bounds.
  __syncthreads();
  float* xch = (float*)smem;
  if (gw == 1) {
#pragma unroll
    for (int t8 = 0; t8 < 8; ++t8)
      *(f32x4*)&xch[wq * 2048 + (t8 * 64 + lane) * 4] = acc[t8 >> 2][t8 & 3];
  }
  __syncthreads();
  if (gw == 0) {
#pragma unroll
    for (int t8 = 0; t8 < 8; ++t8) {
      f32x4 o = *(const f32x4*)&xch[wq * 2048 + (t8 * 64 + lane) * 4];
      acc[t8 >> 2][t8 & 3] += o;
    }

    if (EPI == 0) {
#pragma unroll
      for (int mt = 0; mt < 2; ++mt)
#pragma unroll
        for (int nt = 0; nt < 4; ++nt)
#pragma unroll
          for (int reg = 0; reg < 4; ++reg) {
            int row = m0 + wm + mt * 16 + quad * 4 + reg;
            int col = n0 + wn + nt * 16 + c;
            C[(size_t)row * N + col] = acc[mt][nt][reg];
          }
    } else {
      // fused qkv epilogue: wave covers one head's 64 cols (GBN unchanged).
      const int colb = n0 + wn;
      if (colb < NHEAD * HD) {
        const int h = colb >> 6;
#pragma unroll
        for (int nt = 0; nt < 2; ++nt) {
          const int i = nt * 16 + c;
          const float invf = __expf(-(float)i * (9.210340371976184f / 32.0f));
#pragma unroll
          for (int mt = 0; mt < 2; ++mt)
#pragma unroll
            for (int reg = 0; reg < 4; ++reg) {
              const int s = m0 + wm + mt * 16 + quad * 4 + reg;
              float sn, cs;
              __sincosf((float)s * invf, &sn, &cs);
              const float x1 = acc[mt][nt][reg], x2 = acc[mt][nt + 2][reg];
              bf16_t* q = qb + (size_t)s * H_DIM + h * HD;
              q[i]      = (bf16_t)((x1 * cs - x2 * sn) * 0.125f);
              q[i + 32] = (bf16_t)((x2 * cs + x1 * sn) * 0.125f);
            }
        }
      } else if (colb < NHEAD * HD + KVH * HD) {
        const int kh = (colb - NHEAD * HD) >> 6;
#pragma unroll
        for (int nt = 0; nt < 2; ++nt) {
          const int i = nt * 16 + c;
          const float invf = __expf(-(float)i * (9.210340371976184f / 32.0f));
#pragma unroll
          for (int mt = 0; mt < 2; ++mt)
#pragma unroll
            for (int reg = 0; reg < 4; ++reg) {
              const int s = m0 + wm + mt * 16 + quad * 4 + reg;
              float sn, cs;
              __sincosf((float)s * invf, &sn, &cs);
              const float x1 = acc[mt][nt][reg], x2 = acc[mt][nt + 2][reg];
              bf16_t* kd = ktp + ((size_t)kh * S_LEN + s) * HD;
              kd[i]      = (bf16_t)(x1 * cs - x2 * sn);
              kd[i + 32] = (bf16_t)(x2 * cs + x1 * sn);
            }
        }
      } else {
        const int kh = (colb - NHEAD * HD - KVH * HD) >> 6;
#pragma unroll
        for (int nt = 0; nt < 4; ++nt) {
          const int d = nt * 16 + c;
#pragma unroll
          for (int mt = 0; mt < 2; ++mt) {
            const int sr = m0 + wm + mt * 16 + quad * 4;
            bf16x4 pv;
#pragma unroll
            for (int reg = 0; reg < 4; ++reg) pv[reg] = (bf16_t)acc[mt][nt][reg];
            *(bf16x4*)&vt2[((size_t)kh * HD + d) * S_LEN + sr] = pv;
          }
        }
      }
    }
  }
}

// ---------------- split-K MFMA flash (KVBLK=32, R18/R19 state) ----------------
__global__ __launch_bounds__(256, 4) void flash_split(const bf16_t* __restrict__ qb,
                                                      const bf16_t* __restrict__ kt,
                                                      const bf16_t* __restrict__ vt2,
                                                      float* __restrict__ pbuf,
                                                      bf16_t* __restrict__ attn) {
  __shared__ __align__(16) bf16_t Ks[2][32 * 64];
  __shared__ __align__(16) bf16_t Vs[2][64 * 32];

  const int tid  = threadIdx.x;
  const int lane = tid & 63;
  const int w    = tid >> 6;
  const int e    = (int)gridDim.x - 1 - (int)blockIdx.x;   // long chunks first
  const int kh   = e / NE_PER_KH;
  const int j    = e - kh * NE_PER_KH;

  int qt, chunk, nch;
  if (j < 8) {
    qt = j; chunk = 0; nch = 1;
  } else {
    int j2 = j - 8;
    qt = 8;
    for (;;) {
      nch = (qt + 8) >> 3;          // ceil((qt+1)/8)
      if (j2 < nch) { chunk = j2; break; }
      j2 -= nch; ++qt;
    }
  }
  const int T       = qt + 1;       // 32-key tiles
  const int t_begin = (chunk * T) / nch;
  const int t_end   = ((chunk + 1) * T) / nch;

  const int s0    = qt * 32;
  const int h     = kh * 4 + w;
  const int c     = lane & 15;
  const int quad  = lane >> 4;

  const int idx0 = (c + (quad & 1) * 32) * 4;
  const int idx1 = idx0 + 64;
  const bool hiY = quad >= 2;

  bf16x8 qf[2][2];
#pragma unroll
  for (int rf = 0; rf < 2; ++rf)
#pragma unroll
    for (int ks = 0; ks < 2; ++ks)
      qf[rf][ks] = *(const bf16x8*)(qb + (size_t)(s0 + rf * 16 + c) * H_DIM + h * HD + ks * 32 + quad * 8);

  f32x4 acc[2][4] = {};
  float lsum[2] = {0.f, 0.f};

  const bf16_t* kbase = kt + (size_t)kh * S_LEN * HD;
  const bf16_t* vbase = vt2 + (size_t)kh * HD * S_LEN;

  const int krow = tid >> 3;
  const int kkc  = (tid & 7) ^ (krow & 7);
  const int vrow = tid >> 2;
  const int vkc  = (tid & 3) ^ ((vrow + (vrow >> 2)) & 3);
  const int sbase = w * 64 * 8;

  auto stage = [&](int buf, int tile) {
    const int t0 = tile * 32;
    async_copy16(&Ks[buf][sbase], kbase + (size_t)(t0 + krow) * HD + kkc * 8);
    async_copy16(&Vs[buf][sbase], vbase + (size_t)vrow * S_LEN + t0 + vkc * 8);
  };

  stage(0, t_begin);
  int buf = 0;
  for (int tile = t_begin; tile < t_end; ++tile) {
    const int t0 = tile * 32;
    asm volatile("s_waitcnt vmcnt(0)" ::: "memory");
    __builtin_amdgcn_s_barrier();
    if (tile + 1 < t_end) stage(buf ^ 1, tile + 1);

    const bool masked = (tile == T - 1);

    unsigned pw[2][2][2];   // [rf][kt2][word]
#pragma unroll
    for (int kt2 = 0; kt2 < 2; ++kt2) {
      bf16x8 kf0 = *(const bf16x8*)&Ks[buf][((kt2 * 16 + c) * 8 + ((quad) ^ (c & 7))) * 8];
      bf16x8 kf1 = *(const bf16x8*)&Ks[buf][((kt2 * 16 + c) * 8 + ((4 + quad) ^ (c & 7))) * 8];
#pragma unroll
      for (int rf = 0; rf < 2; ++rf) {
        f32x4 st = {};
        __builtin_amdgcn_s_setprio(1);
        st = __builtin_amdgcn_mfma_f32_16x16x32_bf16(kf0, qf[rf][0], st, 0, 0, 0);
        st = __builtin_amdgcn_mfma_f32_16x16x32_bf16(kf1, qf[rf][1], st, 0, 0, 0);
        __builtin_amdgcn_s_setprio(0);
        const int row = s0 + rf * 16 + c;
        bf16x4 pk;
#pragma unroll
        for (int reg = 0; reg < 4; ++reg) {
          const int key = t0 + kt2 * 16 + quad * 4 + reg;
          float p = __builtin_amdgcn_exp2f(fmaf(st[reg], 1.44269504f, -11.54156036f));
          if (masked && key > row) p = 0.f;
          pk[reg] = (bf16_t)p;
          lsum[rf] += p;
        }
        u32x2 pv2 = __builtin_bit_cast(u32x2, pk);
        pw[rf][kt2][0] = pv2.x;
        pw[rf][kt2][1] = pv2.y;
      }
    }

    bf16x8 vf[4];
#pragma unroll
    for (int dt = 0; dt < 4; ++dt)
      vf[dt] = *(const bf16x8*)&Vs[buf][((dt * 16 + c) * 4 + (quad ^ ((c + (c >> 2)) & 3))) * 8];

#pragma unroll
    for (int rf = 0; rf < 2; ++rf) {
      int lo, hi;
      u32x4 fwv;
      lo = __builtin_amdgcn_ds_bpermute(idx0, (int)pw[rf][0][0]);
      hi = __builtin_amdgcn_ds_bpermute(idx0, (int)pw[rf][1][0]);
      fwv.x = hiY ? (unsigned)hi : (unsigned)lo;
      lo = __builtin_amdgcn_ds_bpermute(idx0, (int)pw[rf][0][1]);
      hi = __builtin_amdgcn_ds_bpermute(idx0, (int)pw[rf][1][1]);
      fwv.y = hiY ? (unsigned)hi : (unsigned)lo;
      lo = __builtin_amdgcn_ds_bpermute(idx1, (int)pw[rf][0][0]);
      hi = __builtin_amdgcn_ds_bpermute(idx1, (int)pw[rf][1][0]);
      fwv.z = hiY ? (unsigned)hi : (unsigned)lo;
      lo = __builtin_amdgcn_ds_bpermute(idx1, (int)pw[rf][0][1]);
      hi = __builtin_amdgcn_ds_bpermute(idx1, (int)pw[rf][1][1]);
      fwv.w = hiY ? (unsigned)hi : (unsigned)lo;
      bf16x8 pa = __builtin_bit_cast(bf16x8, fwv);
      __builtin_amdgcn_s_setprio(1);
#pragma unroll
      for (int dt = 0; dt < 4; ++dt)
        acc[rf][dt] = __builtin_amdgcn_mfma_f32_16x16x32_bf16(pa, vf[dt], acc[rf][dt], 0, 0, 0);
      __builtin_amdgcn_s_setprio(0);
    }
    buf ^= 1;
  }

#pragma unroll
  for (int rf = 0; rf < 2; ++rf) {
    lsum[rf] += __shfl_xor(lsum[rf], 16);
    lsum[rf] += __shfl_xor(lsum[rf], 32);
  }

  __syncthreads();   // all Ks readers done before reusing Ks as lbuf
  if (j < 8) {
    float* lbuf = (float*)&Ks[0][0] + w * 32;
#pragma unroll
    for (int rf = 0; rf < 2; ++rf) lbuf[rf * 16 + c] = lsum[rf];
    asm volatile("s_waitcnt lgkmcnt(0)" ::: "memory");
#pragma unroll
    for (int rf = 0; rf < 2; ++rf)
#pragma unroll
      for (int reg = 0; reg < 4; ++reg) {
        const float inv = 1.0f / lbuf[rf * 16 + quad * 4 + reg];
        const int row = s0 + rf * 16 + quad * 4 + reg;
#pragma unroll
        for (int dt = 0; dt < 4; ++dt)
          attn[(size_t)row * H_DIM + h * HD + dt * 16 + c] = (bf16_t)(acc[rf][dt][reg] * inv);
      }
  } else {
    const int slot = kh * NSPLIT_PER_KH + (j - 8);
    char* ent = (char*)pbuf + (size_t)slot * ENT_BYTES;
    bf16_t* eo = (bf16_t*)ent;
    float*  el = (float*)(ent + 16384);
#pragma unroll
    for (int rf = 0; rf < 2; ++rf) {
#pragma unroll
      for (int dt = 0; dt < 4; ++dt)
#pragma unroll
        for (int reg = 0; reg < 4; ++reg)
          eo[w * 2048 + (rf * 16 + quad * 4 + reg) * 64 + dt * 16 + c] = (bf16_t)acc[rf][dt][reg];
      el[w * 32 + rf * 16 + c] = lsum[rf];
    }
  }
}

// ---------------- reduce: sum bf16 partial chunks, normalize, write attn ----
__global__ __launch_bounds__(256) void flash_reduce(const float* __restrict__ pbuf,
                                                    bf16_t* __restrict__ attn) {
  const int kh = blockIdx.x / 56;
  const int qt = 8 + (blockIdx.x % 56);

  int base = 0;
  for (int q = 8; q < qt; ++q) base += (q + 8) >> 3;
  const int nch = (qt + 8) >> 3;
  base += kh * NSPLIT_PER_KH;

  const int t   = threadIdx.x;
  const int h2  = t >> 6;
  const int row = (t >> 1) & 31;
  const int dh  = t & 1;

  f32x4 o[8] = {};
  float l = 0.f;
  for (int ci = 0; ci < nch; ++ci) {
    const char* ent = (const char*)pbuf + (size_t)(base + ci) * ENT_BYTES;
    const bf16_t* p = (const bf16_t*)ent + h2 * 2048 + row * 64 + dh * 32;
#pragma unroll
    for (int jj = 0; jj < 8; ++jj) {
      bf16x4 v = ((const bf16x4*)p)[jj];
      o[jj][0] += (float)v[0]; o[jj][1] += (float)v[1];
      o[jj][2] += (float)v[2]; o[jj][3] += (float)v[3];
    }
    l += ((const float*)(ent + 16384))[h2 * 32 + row];
  }
  const float inv = 1.0f / l;
  bf16_t* dst = attn + (size_t)(qt * 32 + row) * H_DIM + (kh * 4 + h2) * 64 + dh * 32;
#pragma unroll
  for (int jj = 0; jj < 8; ++jj) {
    bf16x4 ov;
    ov[0] = (bf16_t)(o[jj][0] * inv); ov[1] = (bf16_t)(o[jj][1] * inv);
    ov[2] = (bf16_t)(o[jj][2] * inv); ov[3] = (bf16_t)(o[jj][3] * inv);
    *(bf16x4*)(dst + jj * 4) = ov;
  }
}

// ---------------- launch ----------------
extern "C" void kernel_launch(void* const* d_in, const int* in_sizes, int n_in,
                              void* d_out, int out_size, void* d_ws, size_t ws_size,
                              hipStream_t stream) {
  const float* x     = (const float*)d_in[0];
  const float* w_qkv = (const float*)d_in[1];
  const float* w_o   = (const float*)d_in[2];
  float* out = (float*)d_out;

  char* ws = (char*)d_ws;
  const size_t OVERLAY = (size_t)1280 * 8320 * 4;  // 42.6 MB (pbuf needs 36.1MB)
  bf16_t* x_bf    = (bf16_t*)ws;
  bf16_t* wqkv_bf = (bf16_t*)(ws + (size_t)S_LEN * H_DIM * 2);
  float*  pbuf    = (float*)ws;
  size_t off = OVERLAY;
  bf16_t* wo_bf   = (bf16_t*)(ws + off); off += (size_t)H_DIM * H_DIM * 2;
  bf16_t* q_bf    = (bf16_t*)(ws + off); off += (size_t)S_LEN * H_DIM * 2;
  bf16_t* k_t     = (bf16_t*)(ws + off); off += (size_t)KVH * S_LEN * HD * 2;
  bf16_t* v_t2    = (bf16_t*)(ws + off); off += (size_t)KVH * S_LEN * HD * 2;
  bf16_t* attn    = (bf16_t*)(ws + off); off += (size_t)S_LEN * H_DIM * 2;

  const int ntot = (S_LEN * H_DIM + QKV_N * H_DIM + H_DIM * H_DIM) / 4;
  cast3_kernel<<<(ntot + 255) / 256, 256, 0, stream>>>(x, w_qkv, w_o, x_bf, wqkv_bf, wo_bf);

  gemm_sk<1><<<dim3(QKV_N / GBN, S_LEN / GBM), 512, 0, stream>>>(
      x_bf, wqkv_bf, nullptr, q_bf, k_t, v_t2, S_LEN, QKV_N, H_DIM);

  flash_split<<<8 * NE_PER_KH, 256, 0, stream>>>(q_bf, k_t, v_t2, pbuf, attn);
  flash_reduce<<<8 * 56, 256, 0, stream>>>(pbuf, attn);

  gemm_sk<0><<<dim3(H_DIM / GBN, S_LEN / GBM), 512, 0, stream>>>(
      attn, wo_bf, out, nullptr, nullptr, nullptr, S_LEN, H_DIM, H_DIM);
}